// Round 1
// baseline (114.947 us; speedup 1.0000x reference)
//
#include <hip/hip_runtime.h>
#include <math.h>

#ifndef M_PI
#define M_PI 3.14159265358979323846
#endif

#define NFILT   10
#define THREADS 1024
#define CHUNK   32
#define SEGLEN  (THREADS * CHUNK)   // 32768
#define NSEG    2                   // L = 65536
#define LTOT    (SEGLEN * NSEG)
#define NWAVE   (THREADS / 64)      // 16

__global__ __launch_bounds__(THREADS) void eq_cascade_kernel(
    const float* __restrict__ x,
    const float* __restrict__ w0_in,
    const float* __restrict__ qinv_in,
    const float* __restrict__ gain_in,
    float* __restrict__ out)
{
    __shared__ float  coef[NFILT][5];        // b0,b1,b2,a1,a2 (normalized)
    __shared__ float  mats[NFILT][7][4];     // M_r = A^(2^r), r=0..6, 2x2 row-major
    __shared__ float2 bnd[THREADS];          // per-thread (x_last, x_secondlast)
    __shared__ float2 waveP[NWAVE];          // per-wave inclusive particular totals
    __shared__ float2 saved[2][NFILT + 1];   // per-stage segment-end (last, secondlast), double-buffered

    const int tid  = threadIdx.x;
    const int lane = tid & 63;
    const int wid  = tid >> 6;
    const int b    = blockIdx.x;

    // ---- precompute coefficients + chunk-transfer matrix powers (f64) ----
    if (tid < NFILT) {
        const int k = tid;
        const double w0 = M_PI / (1.0 + exp(-(double)w0_in[b * NFILT + k]));
        const double qi = exp((double)qinv_in[b * NFILT + k]);
        const double A  = exp((double)gain_in[b * NFILT + k]);
        const double cw = cos(w0);
        const double al = sin(w0) * qi * 0.5;
        double B0, B1, B2, A0, A1, A2;
        if (k == 0) {                       // low shelf
            const double Ap1 = A + 1.0, Am1 = A - 1.0, tsa = 2.0 * sqrt(A) * al;
            B0 = A * (Ap1 - Am1 * cw + tsa);
            B1 = 2.0 * A * (Am1 - Ap1 * cw);
            B2 = A * (Ap1 - Am1 * cw - tsa);
            A0 = Ap1 + Am1 * cw + tsa;
            A1 = -2.0 * (Am1 + Ap1 * cw);
            A2 = Ap1 + Am1 * cw - tsa;
        } else if (k == NFILT - 1) {        // high shelf
            const double Ap1 = A + 1.0, Am1 = A - 1.0, tsa = 2.0 * sqrt(A) * al;
            B0 = A * (Ap1 + Am1 * cw + tsa);
            B1 = -2.0 * A * (Am1 + Ap1 * cw);
            B2 = A * (Ap1 + Am1 * cw - tsa);
            A0 = Ap1 - Am1 * cw + tsa;
            A1 = 2.0 * (Am1 - Ap1 * cw);
            A2 = Ap1 - Am1 * cw - tsa;
        } else {                            // peaking
            const double aA = al * A, aiA = al / A;
            B0 = 1.0 + aA;  B1 = -2.0 * cw; B2 = 1.0 - aA;
            A0 = 1.0 + aiA; A1 = B1;        A2 = 1.0 - aiA;
        }
        const double inv = 1.0 / A0;
        const double a1 = A1 * inv, a2 = A2 * inv;
        coef[k][0] = (float)(B0 * inv);
        coef[k][1] = (float)(B1 * inv);
        coef[k][2] = (float)(B2 * inv);
        coef[k][3] = (float)a1;
        coef[k][4] = (float)a2;

        // homogeneous impulse response u_t over one chunk:
        // u_t = -a1 u_{t-1} - a2 u_{t-2}, u_{-1}=1, u_{-2}=0
        double um1 = 1.0, um2 = 0.0, um3 = 0.0;   // u_{t-1}, u_{t-2}, u_{t-3}
        for (int t = 0; t < CHUNK; ++t) {
            const double un = -a1 * um1 - a2 * um2;
            um3 = um2; um2 = um1; um1 = un;
        }
        // A_chunk = [[u31, -a2*u30],[u30, -a2*u29]]
        double M0 = um1, M1 = -a2 * um2, M2 = um2, M3 = -a2 * um3;
        for (int r = 0; r < 7; ++r) {
            mats[k][r][0] = (float)M0; mats[k][r][1] = (float)M1;
            mats[k][r][2] = (float)M2; mats[k][r][3] = (float)M3;
            const double n0 = M0 * M0 + M1 * M2;
            const double n1 = M0 * M1 + M1 * M3;
            const double n2 = M2 * M0 + M3 * M2;
            const double n3 = M2 * M1 + M3 * M3;
            M0 = n0; M1 = n1; M2 = n2; M3 = n3;
        }
    }
    if (tid < NFILT + 1) saved[0][tid] = make_float2(0.f, 0.f);
    __syncthreads();

    const float* xb = x   + (size_t)b * LTOT;
    float*       ob = out + (size_t)b * LTOT;

    float sig[CHUNK];

    for (int s = 0; s < NSEG; ++s) {
        const int p = s & 1, np = p ^ 1;

        const float4* src = reinterpret_cast<const float4*>(xb + (size_t)s * SEGLEN + (size_t)tid * CHUNK);
        #pragma unroll
        for (int i = 0; i < CHUNK / 4; ++i) {
            const float4 v = src[i];
            sig[4 * i + 0] = v.x; sig[4 * i + 1] = v.y;
            sig[4 * i + 2] = v.z; sig[4 * i + 3] = v.w;
        }

        for (int k = 0; k < NFILT; ++k) {
            // ---- Phase A: publish chunk-end boundary (stage-k signal) ----
            bnd[tid] = make_float2(sig[CHUNK - 1], sig[CHUNK - 2]);
            if (tid == THREADS - 1) saved[np][k] = make_float2(sig[CHUNK - 1], sig[CHUNK - 2]);
            __syncthreads();

            const float b0  = coef[k][0], b1c = coef[k][1], b2 = coef[k][2];
            const float a1  = coef[k][3], a2  = coef[k][4];

            float Mreg[7][4];
            #pragma unroll
            for (int r = 0; r < 7; ++r) {
                #pragma unroll
                for (int e = 0; e < 4; ++e) Mreg[r][e] = mats[k][r][e];
            }

            // ---- Phase B: FIR (in place), zero-init recurrence, affine scan ----
            const float2 xm = (tid == 0) ? saved[p][k] : bnd[tid - 1]; // (x_-1, x_-2)

            #pragma unroll
            for (int t = CHUNK - 1; t >= 2; --t)
                sig[t] = b0 * sig[t] + b1c * sig[t - 1] + b2 * sig[t - 2];
            {
                const float c1 = b0 * sig[1] + b1c * sig[0] + b2 * xm.x;
                const float c0 = b0 * sig[0] + b1c * xm.x  + b2 * xm.y;
                sig[1] = c1; sig[0] = c0;
            }

            float y1 = 0.f, y2 = 0.f;                  // particular pass (zero init)
            #pragma unroll
            for (int t = 0; t < CHUNK; ++t) {
                const float y = sig[t] - a1 * y1 - a2 * y2;
                y2 = y1; y1 = y;
            }

            float Sa = y1, Sb = y2;                    // S = (y_31, y_30) particular
            #pragma unroll
            for (int r = 0; r < 6; ++r) {
                const int d = 1 << r;
                const float ta = __shfl_up(Sa, d, 64);
                const float tb = __shfl_up(Sb, d, 64);
                const float na = Sa + Mreg[r][0] * ta + Mreg[r][1] * tb;
                const float nb = Sb + Mreg[r][2] * ta + Mreg[r][3] * tb;
                if (lane >= d) { Sa = na; Sb = nb; }
            }
            if (lane == 63) waveP[wid] = make_float2(Sa, Sb);
            __syncthreads();

            // ---- Phase C: true incoming state, exact second pass ----
            const float2 sv = saved[p][k + 1];         // filter-k output state from prev segment
            float Wa = sv.x, Wb = sv.y;                // (y_-1, y_-2) entering this wave
            for (int j = 0; j < wid; ++j) {
                const float2 Pj = waveP[j];
                const float na = Mreg[6][0] * Wa + Mreg[6][1] * Wb + Pj.x;
                const float nb = Mreg[6][2] * Wa + Mreg[6][3] * Wb + Pj.y;
                Wa = na; Wb = nb;
            }
            #pragma unroll
            for (int r = 0; r < 6; ++r) {              // apply A^lane (powers commute)
                if ((lane >> r) & 1) {
                    const float na = Mreg[r][0] * Wa + Mreg[r][1] * Wb;
                    const float nb = Mreg[r][2] * Wa + Mreg[r][3] * Wb;
                    Wa = na; Wb = nb;
                }
            }
            float Ea = __shfl_up(Sa, 1, 64);
            float Eb = __shfl_up(Sb, 1, 64);
            if (lane == 0) { Ea = 0.f; Eb = 0.f; }

            y1 = Wa + Ea;                              // true y_-1 for this chunk
            y2 = Wb + Eb;                              // true y_-2
            #pragma unroll
            for (int t = 0; t < CHUNK; ++t) {
                const float y = sig[t] - a1 * y1 - a2 * y2;
                sig[t] = y;
                y2 = y1; y1 = y;
            }
        }

        if (tid == THREADS - 1) saved[np][NFILT] = make_float2(sig[CHUNK - 1], sig[CHUNK - 2]);

        float4* dst = reinterpret_cast<float4*>(ob + (size_t)s * SEGLEN + (size_t)tid * CHUNK);
        #pragma unroll
        for (int i = 0; i < CHUNK / 4; ++i)
            dst[i] = make_float4(sig[4 * i + 0], sig[4 * i + 1], sig[4 * i + 2], sig[4 * i + 3]);
    }
}

extern "C" void kernel_launch(void* const* d_in, const int* in_sizes, int n_in,
                              void* d_out, int out_size, void* d_ws, size_t ws_size,
                              hipStream_t stream) {
    const float* x    = (const float*)d_in[0];
    const float* w0   = (const float*)d_in[1];
    const float* qinv = (const float*)d_in[2];
    const float* gain = (const float*)d_in[3];
    float* out = (float*)d_out;

    const int B = in_sizes[1] / NFILT;   // 256 batches (C=1 folded in)
    eq_cascade_kernel<<<B, THREADS, 0, stream>>>(x, w0, qinv, gain, out);
}

// Round 2
// 111.436 us; speedup vs baseline: 1.0315x; 1.0315x over previous
//
#include <hip/hip_runtime.h>
#include <math.h>

#ifndef M_PI
#define M_PI 3.14159265358979323846
#endif

#define NFILT   10
#define THREADS 1024
#define CHUNK   32
#define SEGLEN  (THREADS * CHUNK)   // 32768
#define NSEG    2                   // L = 65536
#define LTOT    (SEGLEN * NSEG)
#define NWAVE   (THREADS / 64)      // 16

__global__ __launch_bounds__(THREADS, 4) void eq_cascade_kernel(
    const float* __restrict__ x,
    const float* __restrict__ w0_in,
    const float* __restrict__ qinv_in,
    const float* __restrict__ gain_in,
    float* __restrict__ out)
{
    __shared__ float  coef[NFILT][5];        // b0,b1,b2,a1,a2 (normalized)
    __shared__ float4 mats4[NFILT][7];       // M_r = A^(2^r), r=0..6, 2x2 row-major
    __shared__ float2 bnd[THREADS];          // per-thread (x_last, x_secondlast)
    __shared__ float2 waveP[NWAVE];          // per-wave inclusive particular totals
    __shared__ float2 saved[2][NFILT + 1];   // per-stage segment-end state, double-buffered

    const int tid  = threadIdx.x;
    const int lane = tid & 63;
    const int wid  = tid >> 6;
    const int b    = blockIdx.x;

    // ---- precompute coefficients + chunk-transfer matrix powers (f64) ----
    if (tid < NFILT) {
        const int k = tid;
        const double w0 = M_PI / (1.0 + exp(-(double)w0_in[b * NFILT + k]));
        const double qi = exp((double)qinv_in[b * NFILT + k]);
        const double A  = exp((double)gain_in[b * NFILT + k]);
        const double cw = cos(w0);
        const double al = sin(w0) * qi * 0.5;
        double B0, B1, B2, A0, A1, A2;
        if (k == 0) {                       // low shelf
            const double Ap1 = A + 1.0, Am1 = A - 1.0, tsa = 2.0 * sqrt(A) * al;
            B0 = A * (Ap1 - Am1 * cw + tsa);
            B1 = 2.0 * A * (Am1 - Ap1 * cw);
            B2 = A * (Ap1 - Am1 * cw - tsa);
            A0 = Ap1 + Am1 * cw + tsa;
            A1 = -2.0 * (Am1 + Ap1 * cw);
            A2 = Ap1 + Am1 * cw - tsa;
        } else if (k == NFILT - 1) {        // high shelf
            const double Ap1 = A + 1.0, Am1 = A - 1.0, tsa = 2.0 * sqrt(A) * al;
            B0 = A * (Ap1 + Am1 * cw + tsa);
            B1 = -2.0 * A * (Am1 + Ap1 * cw);
            B2 = A * (Ap1 + Am1 * cw - tsa);
            A0 = Ap1 - Am1 * cw + tsa;
            A1 = 2.0 * (Am1 - Ap1 * cw);
            A2 = Ap1 - Am1 * cw - tsa;
        } else {                            // peaking
            const double aA = al * A, aiA = al / A;
            B0 = 1.0 + aA;  B1 = -2.0 * cw; B2 = 1.0 - aA;
            A0 = 1.0 + aiA; A1 = B1;        A2 = 1.0 - aiA;
        }
        const double inv = 1.0 / A0;
        const double a1 = A1 * inv, a2 = A2 * inv;
        coef[k][0] = (float)(B0 * inv);
        coef[k][1] = (float)(B1 * inv);
        coef[k][2] = (float)(B2 * inv);
        coef[k][3] = (float)a1;
        coef[k][4] = (float)a2;

        // homogeneous impulse response u_t over one chunk:
        // u_t = -a1 u_{t-1} - a2 u_{t-2}, u_{-1}=1, u_{-2}=0
        double um1 = 1.0, um2 = 0.0, um3 = 0.0;   // u_{t-1}, u_{t-2}, u_{t-3}
        for (int t = 0; t < CHUNK; ++t) {
            const double un = -a1 * um1 - a2 * um2;
            um3 = um2; um2 = um1; um1 = un;
        }
        // A_chunk = [[u31, -a2*u30],[u30, -a2*u29]]
        double M0 = um1, M1 = -a2 * um2, M2 = um2, M3 = -a2 * um3;
        for (int r = 0; r < 7; ++r) {
            mats4[k][r] = make_float4((float)M0, (float)M1, (float)M2, (float)M3);
            const double n0 = M0 * M0 + M1 * M2;
            const double n1 = M0 * M1 + M1 * M3;
            const double n2 = M2 * M0 + M3 * M2;
            const double n3 = M2 * M1 + M3 * M3;
            M0 = n0; M1 = n1; M2 = n2; M3 = n3;
        }
    }
    if (tid < NFILT + 1) saved[0][tid] = make_float2(0.f, 0.f);
    __syncthreads();

    const float* xb = x   + (size_t)b * LTOT;
    float*       ob = out + (size_t)b * LTOT;

    float sig[CHUNK];

    for (int s = 0; s < NSEG; ++s) {
        const int p = s & 1, np = p ^ 1;

        const float4* src = reinterpret_cast<const float4*>(xb + (size_t)s * SEGLEN + (size_t)tid * CHUNK);
        #pragma unroll
        for (int i = 0; i < CHUNK / 4; ++i) {
            const float4 v = src[i];
            sig[4 * i + 0] = v.x; sig[4 * i + 1] = v.y;
            sig[4 * i + 2] = v.z; sig[4 * i + 3] = v.w;
        }

        for (int k = 0; k < NFILT; ++k) {
            // ---- Phase A: publish chunk-end boundary (stage-k signal) ----
            bnd[tid] = make_float2(sig[CHUNK - 1], sig[CHUNK - 2]);
            if (tid == THREADS - 1) saved[np][k] = make_float2(sig[CHUNK - 1], sig[CHUNK - 2]);
            __syncthreads();

            const float b0  = coef[k][0], b1c = coef[k][1], b2 = coef[k][2];
            const float a1  = coef[k][3], a2  = coef[k][4];

            // ---- Phase B: FIR (in place), zero-init recurrence, affine scan ----
            const float2 xm = (tid == 0) ? saved[p][k] : bnd[tid - 1]; // (x_-1, x_-2)

            #pragma unroll
            for (int t = CHUNK - 1; t >= 2; --t)
                sig[t] = b0 * sig[t] + b1c * sig[t - 1] + b2 * sig[t - 2];
            {
                const float c1 = b0 * sig[1] + b1c * sig[0] + b2 * xm.x;
                const float c0 = b0 * sig[0] + b1c * xm.x  + b2 * xm.y;
                sig[1] = c1; sig[0] = c0;
            }

            float y1 = 0.f, y2 = 0.f;                  // particular pass (zero init)
            #pragma unroll
            for (int t = 0; t < CHUNK; ++t) {
                const float y = sig[t] - a1 * y1 - a2 * y2;
                y2 = y1; y1 = y;
            }

            float Sa = y1, Sb = y2;                    // S = (y_31, y_30) particular
            #pragma unroll
            for (int r = 0; r < 6; ++r) {
                const int d = 1 << r;
                const float4 M = mats4[k][r];          // LDS broadcast read
                const float ta = __shfl_up(Sa, d, 64);
                const float tb = __shfl_up(Sb, d, 64);
                const float na = Sa + M.x * ta + M.y * tb;
                const float nb = Sb + M.z * ta + M.w * tb;
                if (lane >= d) { Sa = na; Sb = nb; }
            }
            if (lane == 63) waveP[wid] = make_float2(Sa, Sb);
            __syncthreads();

            // ---- Phase C: true incoming state, exact second pass ----
            const float2 sv = saved[p][k + 1];         // filter-k output state from prev segment
            float Wa = sv.x, Wb = sv.y;                // (y_-1, y_-2) entering this wave
            {
                const float4 M6 = mats4[k][6];
                for (int j = 0; j < wid; ++j) {
                    const float2 Pj = waveP[j];
                    const float na = M6.x * Wa + M6.y * Wb + Pj.x;
                    const float nb = M6.z * Wa + M6.w * Wb + Pj.y;
                    Wa = na; Wb = nb;
                }
            }
            #pragma unroll
            for (int r = 0; r < 6; ++r) {              // apply A^lane (powers commute)
                if ((lane >> r) & 1) {
                    const float4 M = mats4[k][r];
                    const float na = M.x * Wa + M.y * Wb;
                    const float nb = M.z * Wa + M.w * Wb;
                    Wa = na; Wb = nb;
                }
            }
            float Ea = __shfl_up(Sa, 1, 64);
            float Eb = __shfl_up(Sb, 1, 64);
            if (lane == 0) { Ea = 0.f; Eb = 0.f; }

            y1 = Wa + Ea;                              // true y_-1 for this chunk
            y2 = Wb + Eb;                              // true y_-2
            #pragma unroll
            for (int t = 0; t < CHUNK; ++t) {
                const float y = sig[t] - a1 * y1 - a2 * y2;
                sig[t] = y;
                y2 = y1; y1 = y;
            }
        }

        if (tid == THREADS - 1) saved[np][NFILT] = make_float2(sig[CHUNK - 1], sig[CHUNK - 2]);

        float4* dst = reinterpret_cast<float4*>(ob + (size_t)s * SEGLEN + (size_t)tid * CHUNK);
        #pragma unroll
        for (int i = 0; i < CHUNK / 4; ++i)
            dst[i] = make_float4(sig[4 * i + 0], sig[4 * i + 1], sig[4 * i + 2], sig[4 * i + 3]);
    }
}

extern "C" void kernel_launch(void* const* d_in, const int* in_sizes, int n_in,
                              void* d_out, int out_size, void* d_ws, size_t ws_size,
                              hipStream_t stream) {
    const float* x    = (const float*)d_in[0];
    const float* w0   = (const float*)d_in[1];
    const float* qinv = (const float*)d_in[2];
    const float* gain = (const float*)d_in[3];
    float* out = (float*)d_out;

    const int B = in_sizes[1] / NFILT;   // 256 batches (C=1 folded in)
    eq_cascade_kernel<<<B, THREADS, 0, stream>>>(x, w0, qinv, gain, out);
}